// Round 8
// baseline (264.089 us; speedup 1.0000x reference)
//
#include <hip/hip_runtime.h>
#include <math.h>
#include <stdint.h>

// ContentAttention fused, round 8.
// R7 post-mortem: converter is volume-bound (~2.5 TB/s for 262 MB no matter
// the access shape); attn_v5 is L1-datapath-bound (256 KB/CU/tile register
// fill = 4096 cyc >> MFMA 932). R8:
//  - Q's ws round-trip eliminated (its frags have zero cross-block reuse):
//    converter handles K only (131 MB, R2 showed ~26-40us achievable).
//  - attn_v8: A = fp32 from global (L1-hot) + truncation hi/lo split in-reg;
//    B = frag image DMA'd global->LDS (2x64KB dbuf, one barrier/tile, DMA one
//    tile ahead) read via ds_read_b128 -> B moves on the LDS pipe, off L1.
// Fallback v1 (no ws) retained.

#define NB 32
#define NQ 512
#define NK 512
#define ND 1024
#define BK 32
#define NT (ND / BK)            // 32 k-tiles
#define BM1 64                  // fallback rows/block
#define TILE_BYTES 65536        // per (batch,kt): 32 groups x (1KB hi + 1KB lo)
#define WS_K ((size_t)NB * NT * TILE_BYTES)       // 64 MiB K fragment image
#define MASK_BYTES ((size_t)NB * NK * 4)          // 64 KiB
#define WS_V8 (WS_K + MASK_BYTES)

typedef __attribute__((ext_vector_type(8))) short short8;
typedef __attribute__((ext_vector_type(4))) float f32x4;

// ---- RN split (converter; not VALU-bound there) ----
__device__ __forceinline__ void bf_split(float x, unsigned& hbits, float& lo) {
  unsigned u = __float_as_uint(x);
  unsigned r = u + 0x7fffu + ((u >> 16) & 1u);
  hbits = r & 0xffff0000u;
  lo = x - __uint_as_float(hbits);
}
__device__ __forceinline__ unsigned pack_rn(float x0, float x1) {
  unsigned u0 = __float_as_uint(x0), u1 = __float_as_uint(x1);
  unsigned r0 = u0 + 0x7fffu + ((u0 >> 16) & 1u);
  unsigned r1 = u1 + 0x7fffu + ((u1 >> 16) & 1u);
  return (r0 >> 16) | (r1 & 0xffff0000u);
}

// ---- truncation split (attn A-side; ~4.5 VALU/elem, error ~2^-16 rel) ----
__device__ __forceinline__ void cvt8t(const float4& v0, const float4& v1,
                                      short8& hi8, short8& lo8) {
  float f[8] = {v0.x, v0.y, v0.z, v0.w, v1.x, v1.y, v1.z, v1.w};
  unsigned hb[8], lb[8];
#pragma unroll
  for (int i = 0; i < 8; ++i) {
    unsigned u = __float_as_uint(f[i]);
    hb[i] = u & 0xffff0000u;                      // hi = trunc-to-bf16
    float lo = f[i] - __uint_as_float(hb[i]);     // exact residual
    lb[i] = __float_as_uint(lo);
  }
  union { uint4 u; short8 s; } H, L;
  H.u = make_uint4((hb[0] >> 16) | hb[1], (hb[2] >> 16) | hb[3],
                   (hb[4] >> 16) | hb[5], (hb[6] >> 16) | hb[7]);
  L.u = make_uint4((lb[0] >> 16) | (lb[1] & 0xffff0000u),
                   (lb[2] >> 16) | (lb[3] & 0xffff0000u),
                   (lb[4] >> 16) | (lb[5] & 0xffff0000u),
                   (lb[6] >> 16) | (lb[7] & 0xffff0000u));
  hi8 = H.s;
  lo8 = L.s;
}

__device__ __forceinline__ void gl2lds16(const void* g, void* l) {
  __builtin_amdgcn_global_load_lds(
      (const __attribute__((address_space(1))) unsigned int*)g,
      (__attribute__((address_space(3))) unsigned int*)l, 16, 0, 0);
}

// ---------------------------------------------------------------------------
// convert_k_v8: K fp32 -> frag-order ws (K ONLY) via LDS-staged transpose.
// Half a (batch,kt) tile per block (256 rows, 32 KB image). Loads batched
// into regs first (R2-style MLP), then convert+LDS scatter, then linear out.
// ---------------------------------------------------------------------------
__global__ __launch_bounds__(256)
void convert_k_v8(const float* __restrict__ Kg, unsigned char* __restrict__ ws) {
  __shared__ __align__(16) unsigned char sT[32768];
  const int bx = blockIdx.x;               // 0..2047
  const int t = bx >> 1, h = bx & 1;
  const int batch = t >> 5, kt = t & 31;
  const float* sp = Kg + (size_t)batch * NK * ND + kt * BK;
  unsigned char* dp = ws + (size_t)t * TILE_BYTES + (size_t)h * 32768;
  float* maskB = (float*)(ws + WS_K) + batch * NK;

  const int tid = threadIdx.x;
  const int rl0 = tid >> 3, c4 = tid & 7;

  // batch all 8 independent loads (memory-level parallelism)
  float4 v[8];
#pragma unroll
  for (int i = 0; i < 8; ++i) {
    int r = h * 256 + i * 32 + rl0;
    v[i] = *(const float4*)(sp + (size_t)r * ND + c4 * 4);
  }
#pragma unroll
  for (int i = 0; i < 8; ++i) {
    int rl = i * 32 + rl0;
    unsigned h0, h1, h2, h3;
    float l0, l1, l2, l3;
    bf_split(v[i].x, h0, l0); bf_split(v[i].y, h1, l1);
    bf_split(v[i].z, h2, l2); bf_split(v[i].w, h3, l3);
    int l = (rl & 15) | ((c4 >> 1) << 4);
    int base = (rl >> 4) * 2048 + l * 16 + (c4 & 1) * 8;
    *(uint2*)(sT + base) = make_uint2((h0 >> 16) | h1, (h2 >> 16) | h3);
    *(uint2*)(sT + base + 1024) = make_uint2(pack_rn(l0, l1), pack_rn(l2, l3));
    if (kt == 0 && c4 == 0) maskB[h * 256 + rl] = v[i].x;   // K[b][row][0]
  }
  __syncthreads();

  // linear, fully coalesced writeout
#pragma unroll
  for (int i = 0; i < 8; ++i) {
    int c = i * 256 + tid;
    *(uint4*)(dp + (size_t)c * 16) = *(const uint4*)(sT + c * 16);
  }
}

// ---------------------------------------------------------------------------
// MFMA tile helpers
// ---------------------------------------------------------------------------
__device__ __forceinline__ void mfma_tile(const short8 (&AH)[4], const short8 (&AL)[4],
                                          const short8 (&BH)[4], const short8 (&BL)[4],
                                          f32x4 (&acc)[4][4]) {
#pragma unroll
  for (int nt = 0; nt < 4; ++nt)
#pragma unroll
    for (int mt = 0; mt < 4; ++mt)
      acc[mt][nt] = __builtin_amdgcn_mfma_f32_16x16x32_bf16(AH[mt], BH[nt], acc[mt][nt], 0, 0, 0);
#pragma unroll
  for (int nt = 0; nt < 4; ++nt)
#pragma unroll
    for (int mt = 0; mt < 4; ++mt)
      acc[mt][nt] = __builtin_amdgcn_mfma_f32_16x16x32_bf16(AH[mt], BL[nt], acc[mt][nt], 0, 0, 0);
#pragma unroll
  for (int nt = 0; nt < 4; ++nt)
#pragma unroll
    for (int mt = 0; mt < 4; ++mt)
      acc[mt][nt] = __builtin_amdgcn_mfma_f32_16x16x32_bf16(AL[mt], BH[nt], acc[mt][nt], 0, 0, 0);
}

__device__ __forceinline__ void load_a_raw(const float* Qbase, int kt,
                                           int ln15, int quad, float4 (&raw)[8]) {
  const float* pA = Qbase + (size_t)ln15 * ND + kt * BK + quad * 8;
#pragma unroll
  for (int mt = 0; mt < 4; ++mt) {
    const float* p = pA + (size_t)mt * 16 * ND;
    raw[mt * 2] = *(const float4*)p;
    raw[mt * 2 + 1] = *(const float4*)(p + 4);
  }
}
__device__ __forceinline__ void cvt_at(const float4 (&raw)[8],
                                       short8 (&AH)[4], short8 (&AL)[4]) {
#pragma unroll
  for (int mt = 0; mt < 4; ++mt)
    cvt8t(raw[mt * 2], raw[mt * 2 + 1], AH[mt], AL[mt]);
}

// ---------------------------------------------------------------------------
// Shared epilogue: mask + softmax + attn + confidence (proven R5-R7).
// acc layout: row = mt*16 + quad*4 + rg, col = col0 + nt*16 + ln15
// ---------------------------------------------------------------------------
__device__ __forceinline__ void softmax_epilogue(
    f32x4 (&acc)[4][4], float (*sRedA)[64], float (*sRedB)[64],
    const float* maskB, const float* Tp, const float* Bp,
    float* __restrict__ attn, float* __restrict__ conf,
    int batch, int q0, int w, int ln15, int quad, int col0) {
  const float NEGINF = -__builtin_inff();
  float rm[4][4];
#pragma unroll
  for (int mt = 0; mt < 4; ++mt)
#pragma unroll
    for (int rg = 0; rg < 4; ++rg) rm[mt][rg] = NEGINF;

#pragma unroll
  for (int nt = 0; nt < 4; ++nt) {
    int col = col0 + nt * 16 + ln15;
    bool msk = (maskB[col] == 0.0f);
#pragma unroll
    for (int mt = 0; mt < 4; ++mt)
#pragma unroll
      for (int rg = 0; rg < 4; ++rg) {
        float v = msk ? NEGINF : acc[mt][nt][rg];
        acc[mt][nt][rg] = v;
        rm[mt][rg] = fmaxf(rm[mt][rg], v);
      }
  }
#pragma unroll
  for (int mt = 0; mt < 4; ++mt)
#pragma unroll
    for (int rg = 0; rg < 4; ++rg) {
      float v = rm[mt][rg];
#pragma unroll
      for (int d = 1; d < 16; d <<= 1) v = fmaxf(v, __shfl_xor(v, d, 64));
      rm[mt][rg] = v;
    }
  if (ln15 == 0) {
#pragma unroll
    for (int mt = 0; mt < 4; ++mt)
#pragma unroll
      for (int rg = 0; rg < 4; ++rg)
        sRedA[w][mt * 16 + quad * 4 + rg] = rm[mt][rg];
  }
  __syncthreads();

  float gmax[4][4], gsum[4][4];
#pragma unroll
  for (int mt = 0; mt < 4; ++mt)
#pragma unroll
    for (int rg = 0; rg < 4; ++rg) {
      int row = mt * 16 + quad * 4 + rg;
      float m = sRedA[0][row];
#pragma unroll
      for (int c = 1; c < 8; ++c) m = fmaxf(m, sRedA[c][row]);
      gmax[mt][rg] = m;
      gsum[mt][rg] = 0.f;
    }

#pragma unroll
  for (int nt = 0; nt < 4; ++nt)
#pragma unroll
    for (int mt = 0; mt < 4; ++mt)
#pragma unroll
      for (int rg = 0; rg < 4; ++rg) {
        float e = __expf(acc[mt][nt][rg] - gmax[mt][rg]);
        acc[mt][nt][rg] = e;
        gsum[mt][rg] += e;
      }
#pragma unroll
  for (int mt = 0; mt < 4; ++mt)
#pragma unroll
    for (int rg = 0; rg < 4; ++rg) {
      float v = gsum[mt][rg];
#pragma unroll
      for (int d = 1; d < 16; d <<= 1) v += __shfl_xor(v, d, 64);
      gsum[mt][rg] = v;
    }
  if (ln15 == 0) {
#pragma unroll
    for (int mt = 0; mt < 4; ++mt)
#pragma unroll
      for (int rg = 0; rg < 4; ++rg)
        sRedB[w][mt * 16 + quad * 4 + rg] = gsum[mt][rg];
  }
  __syncthreads();
#pragma unroll
  for (int mt = 0; mt < 4; ++mt)
#pragma unroll
    for (int rg = 0; rg < 4; ++rg) {
      int row = mt * 16 + quad * 4 + rg;
      float s = sRedB[0][row];
#pragma unroll
      for (int c = 1; c < 8; ++c) s += sRedB[c][row];
      gsum[mt][rg] = s;
    }

  float* outBase = attn + ((size_t)batch * NQ + q0) * NK;
#pragma unroll
  for (int mt = 0; mt < 4; ++mt)
#pragma unroll
    for (int rg = 0; rg < 4; ++rg) {
      int row = mt * 16 + quad * 4 + rg;
      float inv = 1.0f / gsum[mt][rg];
#pragma unroll
      for (int nt = 0; nt < 4; ++nt)
        outBase[(size_t)row * NK + col0 + nt * 16 + ln15] = acc[mt][nt][rg] * inv;
    }

  if (w == 0 && ln15 == 0) {
    float tv = Tp[0], bv = Bp[0];
#pragma unroll
    for (int mt = 0; mt < 4; ++mt)
#pragma unroll
      for (int rg = 0; rg < 4; ++rg) {
        int row = mt * 16 + quad * 4 + rg;
        float lse = gmax[mt][rg] + __logf(gsum[mt][rg]);
        float t = (lse + bv) * tv;
        conf[(size_t)batch * NQ + q0 + row] = 1.0f / (1.0f + __expf(-t));
      }
  }
}

// ---------------------------------------------------------------------------
// attn_v8: A fp32 from global + in-reg trunc split; B frags via LDS DMA dbuf.
// Block: 512 thr / 8 waves, 64q x 512k, wave tile 64x64. Grid 256. 1 block/CU.
// ---------------------------------------------------------------------------
__global__ __launch_bounds__(512, 1)
void attn_v8(const float* __restrict__ Qg, const unsigned char* __restrict__ ws,
             const float* __restrict__ Tp, const float* __restrict__ Bp,
             float* __restrict__ attn, float* __restrict__ conf) {
  __shared__ __align__(16) unsigned char sB[2][TILE_BYTES];   // 2 x 64 KB
  __shared__ float sRedA[8][64];
  __shared__ float sRedB[8][64];

  const int tid = threadIdx.x;
  const int g = blockIdx.x;                 // 0..255
  const int batch = (g & 7) | (((g >> 3) & 3) << 3);   // co-XCD per batch
  const int q0 = (g >> 5) * 64;
  const int ln = tid & 63, w = tid >> 6;    // 8 waves
  const int ln15 = ln & 15, quad = ln >> 4;
  const int col0 = w * 64;

  const unsigned char* wsK = ws + (size_t)batch * NT * TILE_BYTES;
  const float* maskB = (const float*)(ws + WS_K) + batch * NK;
  const float* Qbase = Qg + ((size_t)batch * NQ + q0) * ND;

  f32x4 acc[4][4];
#pragma unroll
  for (int mt = 0; mt < 4; ++mt)
#pragma unroll
    for (int nt = 0; nt < 4; ++nt) acc[mt][nt] = (f32x4){0.f, 0.f, 0.f, 0.f};

  float4 raw[8];
  short8 aH[4], aL[4];
  short8 bH[4], bL[4];

  // ---- prologue ----
  // DMA tile 0 into buf0: each wave stages 8 KB (8 x 1KB wave-chunks).
#pragma unroll
  for (int c = 0; c < 8; ++c) {
    int byte = ((w * 8 + c) * 64 + ln) * 16;
    gl2lds16(wsK + byte, sB[0] + byte);
  }
  load_a_raw(Qbase, 0, ln15, quad, raw);
  cvt_at(raw, aH, aL);
  load_a_raw(Qbase, 1, ln15, quad, raw);

  for (int kt = 0; kt < NT; ++kt) {
    const int cur = kt & 1;
    __syncthreads();              // drains DMA(kt) issued one tile ago

    if (kt + 1 < NT) {            // DMA(kt+1) -> other buffer, full tile ahead
      const unsigned char* tb = wsK + (size_t)(kt + 1) * TILE_BYTES;
#pragma unroll
      for (int c = 0; c < 8; ++c) {
        int byte = ((w * 8 + c) * 64 + ln) * 16;
        gl2lds16(tb + byte, sB[cur ^ 1] + byte);
      }
    }

    // B fragments from LDS (ds_read_b128, on the LDS pipe, off L1)
#pragma unroll
    for (int i = 0; i < 4; ++i) {
      int off = (w * 4 + i) * 2048 + ln * 16;
      bH[i] = *(const short8*)(sB[cur] + off);
      bL[i] = *(const short8*)(sB[cur] + off + 1024);
    }

    mfma_tile(aH, aL, bH, bL, acc);

    if (kt + 1 < NT) {
      cvt_at(raw, aH, aL);        // raw(kt+1) drained during MFMA
      if (kt + 2 < NT) load_a_raw(Qbase, kt + 2, ln15, quad, raw);
    }
  }

  softmax_epilogue(acc, sRedA, sRedB, maskB, Tp, Bp, attn, conf,
                   batch, q0, w, ln15, quad, col0);
}

// ---------------------------------------------------------------------------
// Fallback: single-kernel path (no ws) — R1 structure.
// ---------------------------------------------------------------------------
__device__ __forceinline__ int lds_off_write(int r, int c4) {
  int slot = ((c4 >> 1) + (r >> 1)) & 3;
  return r * 32 + slot * 8 + (c4 & 1) * 4;
}
__device__ __forceinline__ int lds_off_read(int r, int quad) {
  int slot = (quad + (r >> 1)) & 3;
  return r * 32 + slot * 8;
}

__global__ __launch_bounds__(256, 1)
void attn_fused_v1(const float* __restrict__ Qg, const float* __restrict__ Kg,
                   const float* __restrict__ Tp, const float* __restrict__ Bp,
                   float* __restrict__ attn, float* __restrict__ conf) {
  __shared__ __align__(16) unsigned short sAhi[BM1 * BK];
  __shared__ __align__(16) unsigned short sAlo[BM1 * BK];
  __shared__ __align__(16) unsigned short sBhi[NK * BK];
  __shared__ __align__(16) unsigned short sBlo[NK * BK];
  __shared__ float sRedA[4][BM1];
  __shared__ float sRedB[4][BM1];

  const int tid = threadIdx.x;
  const int g = blockIdx.x;
  const int batch = (g & 7) | (((g >> 3) & 3) << 3);
  const int q0 = (g >> 5) * BM1;
  const int ln = tid & 63, w = tid >> 6;
  const int ln15 = ln & 15, quad = ln >> 4;
  const int wn0 = w * 128;

  const float* Qp = Qg + ((size_t)batch * NQ + q0) * ND;
  const float* Kp = Kg + (size_t)batch * NK * ND;

  f32x4 acc[4][8];
#pragma unroll
  for (int mt = 0; mt < 4; ++mt)
#pragma unroll
    for (int nt = 0; nt < 8; ++nt) acc[mt][nt] = (f32x4){0.f, 0.f, 0.f, 0.f};

  float4 pb[16], pa[2];
#pragma unroll
  for (int i = 0; i < 16; ++i) {
    int idx = tid + 256 * i, r = idx >> 3, c4 = idx & 7;
    pb[i] = *(const float4*)(Kp + (size_t)r * ND + c4 * 4);
  }
#pragma unroll
  for (int i = 0; i < 2; ++i) {
    int idx = tid + 256 * i, r = idx >> 3, c4 = idx & 7;
    pa[i] = *(const float4*)(Qp + (size_t)r * ND + c4 * 4);
  }

  for (int kt = 0; kt < NT; ++kt) {
    if (kt) __syncthreads();
#pragma unroll
    for (int i = 0; i < 2; ++i) {
      int idx = tid + 256 * i, r = idx >> 3, c4 = idx & 7;
      int off = lds_off_write(r, c4);
      unsigned h0, h1, h2, h3; float l0, l1, l2, l3;
      bf_split(pa[i].x, h0, l0); bf_split(pa[i].y, h1, l1);
      bf_split(pa[i].z, h2, l2); bf_split(pa[i].w, h3, l3);
      *(uint2*)(&sAhi[off]) = make_uint2((h0 >> 16) | h1, (h2 >> 16) | h3);
      *(uint2*)(&sAlo[off]) = make_uint2(pack_rn(l0, l1), pack_rn(l2, l3));
    }
#pragma unroll
    for (int i = 0; i < 16; ++i) {
      int idx = tid + 256 * i, r = idx >> 3, c4 = idx & 7;
      int off = lds_off_write(r, c4);
      unsigned h0, h1, h2, h3; float l0, l1, l2, l3;
      bf_split(pb[i].x, h0, l0); bf_split(pb[i].y, h1, l1);
      bf_split(pb[i].z, h2, l2); bf_split(pb[i].w, h3, l3);
      *(uint2*)(&sBhi[off]) = make_uint2((h0 >> 16) | h1, (h2 >> 16) | h3);
      *(uint2*)(&sBlo[off]) = make_uint2(pack_rn(l0, l1), pack_rn(l2, l3));
    }
    __syncthreads();

    if (kt < NT - 1) {
      const float* Kq = Kp + (kt + 1) * BK;
      const float* Qq = Qp + (kt + 1) * BK;
#pragma unroll
      for (int i = 0; i < 16; ++i) {
        int idx = tid + 256 * i, r = idx >> 3, c4 = idx & 7;
        pb[i] = *(const float4*)(Kq + (size_t)r * ND + c4 * 4);
      }
#pragma unroll
      for (int i = 0; i < 2; ++i) {
        int idx = tid + 256 * i, r = idx >> 3, c4 = idx & 7;
        pa[i] = *(const float4*)(Qq + (size_t)r * ND + c4 * 4);
      }
    }

    short8 ahi[4], alo[4];
#pragma unroll
    for (int mt = 0; mt < 4; ++mt) {
      int off = lds_off_read(mt * 16 + ln15, quad);
      ahi[mt] = *(const short8*)(&sAhi[off]);
      alo[mt] = *(const short8*)(&sAlo[off]);
    }
#pragma unroll
    for (int nt = 0; nt < 8; ++nt) {
      int off = lds_off_read(wn0 + nt * 16 + ln15, quad);
      short8 bhi = *(const short8*)(&sBhi[off]);
      short8 blo = *(const short8*)(&sBlo[off]);
#pragma unroll
      for (int mt = 0; mt < 4; ++mt) {
        acc[mt][nt] = __builtin_amdgcn_mfma_f32_16x16x32_bf16(ahi[mt], bhi, acc[mt][nt], 0, 0, 0);
        acc[mt][nt] = __builtin_amdgcn_mfma_f32_16x16x32_bf16(ahi[mt], blo, acc[mt][nt], 0, 0, 0);
        acc[mt][nt] = __builtin_amdgcn_mfma_f32_16x16x32_bf16(alo[mt], bhi, acc[mt][nt], 0, 0, 0);
      }
    }
  }

  const float NEGINF = -__builtin_inff();
  float rm[4][4];
#pragma unroll
  for (int mt = 0; mt < 4; ++mt)
#pragma unroll
    for (int rg = 0; rg < 4; ++rg) rm[mt][rg] = NEGINF;
#pragma unroll
  for (int nt = 0; nt < 8; ++nt) {
    int col = wn0 + nt * 16 + ln15;
    bool msk = (Kp[(size_t)col * ND] == 0.0f);
#pragma unroll
    for (int mt = 0; mt < 4; ++mt)
#pragma unroll
      for (int rg = 0; rg < 4; ++rg) {
        float v = msk ? NEGINF : acc[mt][nt][rg];
        acc[mt][nt][rg] = v;
        rm[mt][rg] = fmaxf(rm[mt][rg], v);
      }
  }
#pragma unroll
  for (int mt = 0; mt < 4; ++mt)
#pragma unroll
    for (int rg = 0; rg < 4; ++rg) {
      float v = rm[mt][rg];
#pragma unroll
      for (int d = 1; d < 16; d <<= 1) v = fmaxf(v, __shfl_xor(v, d, 64));
      rm[mt][rg] = v;
    }
  if (ln15 == 0)
#pragma unroll
    for (int mt = 0; mt < 4; ++mt)
#pragma unroll
      for (int rg = 0; rg < 4; ++rg)
        sRedA[w][mt * 16 + quad * 4 + rg] = rm[mt][rg];
  __syncthreads();

  float gmax[4][4], gsum[4][4];
#pragma unroll
  for (int mt = 0; mt < 4; ++mt)
#pragma unroll
    for (int rg = 0; rg < 4; ++rg) {
      int row = mt * 16 + quad * 4 + rg;
      gmax[mt][rg] = fmaxf(fmaxf(sRedA[0][row], sRedA[1][row]),
                           fmaxf(sRedA[2][row], sRedA[3][row]));
      gsum[mt][rg] = 0.f;
    }
#pragma unroll
  for (int nt = 0; nt < 8; ++nt)
#pragma unroll
    for (int mt = 0; mt < 4; ++mt)
#pragma unroll
      for (int rg = 0; rg < 4; ++rg) {
        float e = __expf(acc[mt][nt][rg] - gmax[mt][rg]);
        acc[mt][nt][rg] = e;
        gsum[mt][rg] += e;
      }
#pragma unroll
  for (int mt = 0; mt < 4; ++mt)
#pragma unroll
    for (int rg = 0; rg < 4; ++rg) {
      float v = gsum[mt][rg];
#pragma unroll
      for (int d = 1; d < 16; d <<= 1) v += __shfl_xor(v, d, 64);
      gsum[mt][rg] = v;
    }
  if (ln15 == 0)
#pragma unroll
    for (int mt = 0; mt < 4; ++mt)
#pragma unroll
      for (int rg = 0; rg < 4; ++rg)
        sRedB[w][mt * 16 + quad * 4 + rg] = gsum[mt][rg];
  __syncthreads();
#pragma unroll
  for (int mt = 0; mt < 4; ++mt)
#pragma unroll
    for (int rg = 0; rg < 4; ++rg) {
      int row = mt * 16 + quad * 4 + rg;
      gsum[mt][rg] = sRedB[0][row] + sRedB[1][row] + sRedB[2][row] + sRedB[3][row];
    }

  float* outBase = attn + ((size_t)batch * NQ + q0) * NK;
#pragma unroll
  for (int mt = 0; mt < 4; ++mt)
#pragma unroll
    for (int rg = 0; rg < 4; ++rg) {
      int row = mt * 16 + quad * 4 + rg;
      float inv = 1.0f / gsum[mt][rg];
#pragma unroll
      for (int nt = 0; nt < 8; ++nt)
        outBase[(size_t)row * NK + wn0 + nt * 16 + ln15] = acc[mt][nt][rg] * inv;
    }
  if (w == 0 && ln15 == 0) {
    float tv = Tp[0], bv = Bp[0];
#pragma unroll
    for (int mt = 0; mt < 4; ++mt)
#pragma unroll
      for (int rg = 0; rg < 4; ++rg) {
        int row = mt * 16 + quad * 4 + rg;
        float lse = gmax[mt][rg] + __logf(gsum[mt][rg]);
        float t = (lse + bv) * tv;
        conf[(size_t)batch * NQ + q0 + row] = 1.0f / (1.0f + __expf(-t));
      }
  }
}

extern "C" void kernel_launch(void* const* d_in, const int* in_sizes, int n_in,
                              void* d_out, int out_size, void* d_ws, size_t ws_size,
                              hipStream_t stream) {
  const float* q = (const float*)d_in[0];
  const float* k = (const float*)d_in[1];
  const float* temp = (const float*)d_in[2];
  const float* bias = (const float*)d_in[3];
  float* attn = (float*)d_out;
  float* conf = attn + (size_t)NB * NQ * NK;

  if (ws_size >= WS_V8) {
    hipLaunchKernelGGL(convert_k_v8, dim3(NB * NT * 2), dim3(256), 0, stream,
                       k, (unsigned char*)d_ws);
    hipLaunchKernelGGL(attn_v8, dim3(256), dim3(512), 0, stream,
                       q, (const unsigned char*)d_ws, temp, bias, attn, conf);
  } else {
    hipLaunchKernelGGL(attn_fused_v1, dim3(NB * (NQ / BM1)), dim3(256), 0, stream,
                       q, k, temp, bias, attn, conf);
  }
}